// Round 6
// baseline (16923.222 us; speedup 1.0000x reference)
//
#include <hip/hip_runtime.h>
#include <hip/hip_bf16.h>
#include <cstdint>
#include <cstddef>

using bf16 = __hip_bfloat16;
typedef __attribute__((ext_vector_type(8))) short   bf16x8_t;  // 8 bf16 (4 VGPRs)
typedef __attribute__((ext_vector_type(4))) float   f32x4_t;   // mfma accumulator

#define MFMA(acc, a, b) acc = __builtin_amdgcn_mfma_f32_16x16x32_bf16(a, b, acc, 0,0,0)

// ---------------- workspace byte offsets (total 33,455,360 B; known-good budget 34.58 MB) ----
#define XT_OFF   ((size_t)0)            // [32 ci][256 t][16 r][96] bf16
#define UF_OFF   ((size_t)25165824)     // [336][128] bf16 gate-ordered U strips (fwd)
#define UB_OFF   ((size_t)25251840)     // (bwd)
#define WF_OFF   ((size_t)25337856)     // fwd W shifted: row k -> gru_W[k-1], k=1..64
#define WB_OFF   ((size_t)25423872)     // bwd W: row k -> bgru_W[k], k=0..64
#define DW_OFF   ((size_t)25509888)     // dec_W strips [4][64][256] (K 0..99=h, 128..227=hb)
#define MW_OFF   ((size_t)25640960)     // mean_W^T strips [4][64][64]
#define SAV_OFF  ((size_t)25673728)     // saved h_back [32 ci][64 slot][1696] bf16 (stride 104 + guard)
#define SPL_OFF  ((size_t)32620544)     // spills [32 ci][4][1696] bf16
#define RING_OFF ((size_t)33054720)     // fills  [32 ci][4][16*96] bf16
#define CST_OFF  ((size_t)33447936)     // fp32: b0f,b1f,b0b,b1b[336 ea], mb[256], db[256]
#define WS_NEED  ((size_t)33455360)

// ---------------- static schedule (mask t%16==0, batch-shared) ----------------
struct Op { uint8_t type, t; int8_t lvl, save, hsrc, srcidx, gisrc, aux; };
// type: 0=BCELL(bwd,X=xT) 1=FA(fwd,X=xT) 2=FF(fwd,X=ring[lvl]) 3=DEC 4=CH(bwd,X=ring[t] if gisrc)
// hsrc: 0=CUR 1=SAV 2=SPL ; aux: CH spill slot (-1 none) ; DEC: save=ring write slot
struct Sched { Op ops[960]; short n; };

constexpr int slot_of(int tp){ int k=(tp-1)/16; int m=tp%16;
  int pos = (m==9)?0:((m==13)?1:((m==15)?2:3)); return 4*k+pos; }

constexpr Sched build_sched(){
  Sched s{}; int i=0;
  for (int t=255; t>=1; --t){
    int tp=t+1, m=tp%16; int8_t sv=-1;
    if (m==9||m==13||m==15||m==0) sv=(int8_t)slot_of(tp);
    s.ops[i++] = Op{(uint8_t)0,(uint8_t)t,(int8_t)0,sv,(int8_t)0,(int8_t)0,(int8_t)0,(int8_t)0};
  }
  s.ops[i++] = Op{(uint8_t)1,(uint8_t)0,(int8_t)0,(int8_t)-1,(int8_t)0,(int8_t)0,(int8_t)0,(int8_t)0}; // FA(0)
  for (int blk=0; blk<16; ++blk){
    int ba=16*blk; bool last=(blk==15);
    int s16=slot_of(ba+16), s9=slot_of(ba+9), s13=slot_of(ba+13), s15=slot_of(ba+15);
#define PD(dt,lv,hs,si,wsl) s.ops[i++]=Op{(uint8_t)3,(uint8_t)(ba+(dt)),(int8_t)(lv),(int8_t)(wsl),(int8_t)(hs),(int8_t)(si),(int8_t)0,(int8_t)0};
#define PC(hs,si,gs,sp,sl)  s.ops[i++]=Op{(uint8_t)4,(uint8_t)(sl),(int8_t)0,(int8_t)-1,(int8_t)(hs),(int8_t)(si),(int8_t)(gs),(int8_t)(sp)};
#define PF(ft,rs)           s.ops[i++]=Op{(uint8_t)2,(uint8_t)(ba+(ft)),(int8_t)(rs),(int8_t)-1,(int8_t)0,(int8_t)0,(int8_t)0,(int8_t)0};
#define PA(ft)              s.ops[i++]=Op{(uint8_t)1,(uint8_t)(ba+(ft)),(int8_t)0,(int8_t)-1,(int8_t)0,(int8_t)0,(int8_t)0,(int8_t)0};
    PD(8,3,1,s16, 0)
    PC(1,s9,1,0, 0)  PC(0,0,0,1, 0) PC(0,0,0,-1, 0) PC(0,0,0,-1, 0)   // nb8(sp0) nb7(sp1) nb6 nb5
    PD(4,2,2,0, 1)
    PC(0,0,1,2, 1) PC(0,0,0,-1, 0)                                     // nb4'(sp2) nb3
    PD(2,1,2,2, 2)
    PC(0,0,1,-1, 2)                                                    // nb2''
    PD(1,0,0,0, 3)
    PF(1,3) PF(2,2)
    PD(3,0,2,2, 2)
    PF(3,2) PF(4,1)
    PD(6,1,2,0, 1)
    PC(2,1,1,-1, 1)                                                    // nb6' = gru(ns6, sp1)
    PD(5,0,0,0, 3)
    PF(5,3) PF(6,1)
    PD(7,0,2,0, 2)
    PF(7,2) PF(8,0)
    PD(12,2,1,s16, 0)
    PC(1,s13,1,3, 0) PC(0,0,0,-1, 0)                                   // nb12(sp3) nb11
    PD(10,1,2,3, 1)
    PC(0,0,1,-1, 1)                                                    // nb10'
    PD(9,0,0,0, 3)
    PF(9,3) PF(10,1)
    PD(11,0,2,3, 2)
    PF(11,2) PF(12,0)
    PD(14,1,1,s16, 1)
    PC(1,s15,1,-1, 1)                                                  // nb14
    PD(13,0,0,0, 3)
    PF(13,3) PF(14,1)
    PD(15,0,1,s16, 2)
    if(!last){ PF(15,2); PA(16); }
#undef PD
#undef PC
#undef PF
#undef PA
  }
  s.n=(short)i; return s;
}
__constant__ Sched g_sched = build_sched();

// ---------------- prep kernels (fp32 inputs -> bf16 internal) ----------------
__global__ void k_xt(const float* __restrict__ a, bf16* __restrict__ xT){
  int b=blockIdx.x, t=threadIdx.x;
  int ci=b>>4, r=b&15;
  bf16* dst = xT + (((size_t)ci*256 + t)*16 + r)*96;
  const float* ap = a + (size_t)b*64*256*3;
  for (int c=0;c<64;++c) dst[c] = __float2bfloat16(ap[((size_t)c*256+t)*3]);
  dst[64] = __float2bfloat16(ap[(size_t)t*3 + 2]);
  bf16 z = __float2bfloat16(0.f);
  for (int c=65;c<96;++c) dst[c]=z;
}

__global__ void k_obs(const float* __restrict__ a, float* __restrict__ out){
  int b=blockIdx.x, d=threadIdx.x; // 64 threads
  for (int kk=0;kk<16;++kk){ int t=kk*16;
    float v = (d<63)? a[(((size_t)b*64 + d+1)*256 + t)*3]
                    : a[((size_t)b*64*256 + t)*3 + 2];
    out[((size_t)b*64 + d)*256 + t] = v;
  }
}

__global__ void k_wt(const float* __restrict__ gru_U, const float* __restrict__ bgru_U,
                     const float* __restrict__ gru_W, const float* __restrict__ bgru_W,
                     bf16* Uf, bf16* Ub, bf16* Wf, bf16* Wb){
  int c=blockIdx.x, k=threadIdx.x; // 336 x 128
  int g=c/48, rm=c%48, e=rm/16, l=rm%16, j=16*g+l;
  bool val = j<100; int gc = val? (e*100+j) : 0;
  bf16 z = __float2bfloat16(0.f);
  Uf[(size_t)c*128+k] = (val&&k<100)? __float2bfloat16(gru_U[k*300+gc]) : z;
  Ub[(size_t)c*128+k] = (val&&k<100)? __float2bfloat16(bgru_U[k*300+gc]) : z;
  Wf[(size_t)c*128+k] = (val&&k>=1&&k<=64)? __float2bfloat16(gru_W[(k-1)*300+gc]) : z;
  Wb[(size_t)c*128+k] = (val&&k<65)? __float2bfloat16(bgru_W[k*300+gc]) : z;
}

__global__ void k_decw(const float* __restrict__ dec_W, bf16* dWt){
  int idx=blockIdx.x; int lvl=idx/64, n=idx%64; int k=threadIdx.x;
  float v=0.f;
  if (n<50){
    if (k<100) v = dec_W[(lvl*200+k)*50+n];
    else if (k>=128 && k<228) v = dec_W[(lvl*200+k-28)*50+n];
  }
  dWt[(size_t)idx*256+k] = __float2bfloat16(v);
}

__global__ void k_mw(const float* __restrict__ mean_W, bf16* MW){
  int idx=blockIdx.x; int lvl=idx/64, c=idx%64; int k=threadIdx.x; // 64
  MW[(size_t)idx*64+k] = (k<50)? __float2bfloat16(mean_W[(lvl*50+k)*64+c]) : __float2bfloat16(0.f);
}

__global__ void k_consts(const float* __restrict__ gru_b, const float* __restrict__ bgru_b,
                         const float* __restrict__ mean_b, const float* __restrict__ dec_b,
                         float* cst){
  int tid=threadIdx.x;
  for (int u=tid; u<336; u+=256){
    int c=u; int g=c/48, rm=c%48, e=rm/16, l=rm%16, j=16*g+l;
    float b0f=0,b1f=0,b0b=0,b1b=0;
    if (j<100){ int gc=e*100+j;
      b0f=gru_b[gc];  b1f=gru_b[300+gc];
      b0b=bgru_b[gc]; b1b=bgru_b[300+gc]; }
    cst[u]=b0f; cst[336+u]=b1f; cst[672+u]=b0b; cst[1008+u]=b1b;
  }
  if (tid<256){
    int lvl=tid/64, m=tid%64;
    cst[1344+tid]=mean_b[lvl*64+m];
    cst[1600+tid]=(m<50)? dec_b[lvl*50+m] : 0.f;
  }
}

// ---------------- main persistent kernel: 8 WGs x 4 waves; wave = one 16-row chain, NO barriers --
__launch_bounds__(256, 1)
__global__ void naomi_main(unsigned char* __restrict__ ws, float* __restrict__ out){
  const int tid=threadIdx.x, wg=blockIdx.x;
  const int lane=tid&63, wv=tid>>6;
  const int l15=lane&15, q=lane>>4;
  const int ci = wg*4 + wv;                 // chain 0..31, rows 16ci..16ci+15

  const bf16* Uf = (const bf16*)(ws + UF_OFF);
  const bf16* Ub = (const bf16*)(ws + UB_OFF);
  const bf16* Wf = (const bf16*)(ws + WF_OFF);
  const bf16* Wb = (const bf16*)(ws + WB_OFF);
  const bf16* dW = (const bf16*)(ws + DW_OFF);
  const bf16* MW = (const bf16*)(ws + MW_OFF);
  const float* cst = (const float*)(ws + CST_OFF);
  const bf16* xTc = (const bf16*)(ws + XT_OFF) + (size_t)ci*256*16*96;
  bf16* savc  = (bf16*)(ws + SAV_OFF) + (size_t)ci*64*1696;
  bf16* splc  = (bf16*)(ws + SPL_OFF) + (size_t)ci*4*1696;
  bf16* ringc = (bf16*)(ws + RING_OFF) + (size_t)ci*4*1536;

  // LDS: per-wave slice 9088 B: s_h[1696] | s_hbk[1696] | s_dec[1152] (bf16 elems)
  __shared__ alignas(16) unsigned char smem[36352];
  unsigned char* base = smem + wv*9088;
  bf16* s_h   = (bf16*)(base + 0);
  bf16* s_hbk = (bf16*)(base + 3392);
  bf16* s_dec = (bf16*)(base + 6784);
  { uint32_t* zp = (uint32_t*)base;
    for (int u=lane; u<2272; u+=64) zp[u]=0u; }

  // biases in registers (g compile-time indexed; fwd/bwd selected by uniform ternary)
  float bzsF[7], brsF[7], b0nF[7], b1nF[7];
  float bzsB[7], brsB[7], b0nB[7], b1nB[7];
  #pragma unroll
  for (int g=0; g<7; ++g){
    int cz = 48*g + l15;
    bzsF[g] = cst[cz]     + cst[336+cz];
    brsF[g] = cst[cz+16]  + cst[336+cz+16];
    b0nF[g] = cst[cz+32];
    b1nF[g] = cst[336+cz+32];
    bzsB[g] = cst[672+cz]    + cst[1008+cz];
    brsB[g] = cst[672+cz+16] + cst[1008+cz+16];
    b0nB[g] = cst[672+cz+32];
    b1nB[g] = cst[1008+cz+32];
  }

  // fp32 master state in registers: this lane owns (r=4q+i, j=16g+l15)
  float h_reg[7][4], hb_reg[7][4];
  #pragma unroll
  for (int g=0;g<7;++g){
    #pragma unroll
    for (int i=0;i<4;++i){ h_reg[g][i]=0.f; hb_reg[g][i]=0.f; }
  }

  // X prefetch (1 op ahead)
  bf16x8_t pX[3];
  { const bf16* px = xTc + ((size_t)g_sched.ops[0].t*16 + l15)*96 + 8*q;
    #pragma unroll
    for (int s=0;s<3;++s) pX[s] = *(const bf16x8_t*)(px + 32*s);
  }

  const int nops = g_sched.n;
  for (int io=0; io<nops; ++io){
    const Op op = g_sched.ops[io];
    const Op on = g_sched.ops[(io+1<nops)? io+1 : io];
    if (op.type != 3){
      const bool fwd  = (op.type==1)||(op.type==2);
      const bool isCH = (op.type==4);
      const bool hasX = (op.type<=2) || (isCH && op.gisrc==1);
      // ---- A fragments (h operand), stride 104 everywhere ----
      bf16x8_t aH[4];
      if (fwd || op.hsrc==0){
        const bf16* hp = (fwd? s_h : s_hbk) + l15*104 + 8*q;
        #pragma unroll
        for (int s=0;s<4;++s) aH[s] = *(const bf16x8_t*)(hp + 32*s);
      } else {
        const bf16* hp = ((op.hsrc==1)? savc : splc) + (int)op.srcidx*1696 + l15*104 + 8*q;
        #pragma unroll
        for (int s=0;s<4;++s) aH[s] = *(const bf16x8_t*)(hp + 32*s);
      }
      // ---- X fragments ----
      bf16x8_t aX[3];
      if (op.type==0 || op.type==1){
        #pragma unroll
        for (int s=0;s<3;++s) aX[s] = pX[s];
      } else if (hasX){
        int rs = (op.type==2)? (int)op.lvl : (int)op.t;
        const bf16* xp = ringc + rs*1536 + l15*96 + 8*q;
        #pragma unroll
        for (int s=0;s<3;++s) aX[s] = *(const bf16x8_t*)(xp + 32*s);
      }
      // ---- hold values for CH from sav/spl ----
      float holdv[7][4];
      if (isCH && op.hsrc!=0){
        const bf16* hp = ((op.hsrc==1)? savc : splc) + (int)op.srcidx*1696;
        #pragma unroll
        for (int g=0; g<7; ++g){
          int j = 16*g + l15;
          if (j < 100){
            #pragma unroll
            for (int i=0;i<4;++i) holdv[g][i] = __bfloat162float(hp[(4*q+i)*104 + j]);
          }
        }
      }
      // ---- prefetch X for next op (early: ~full op of lead time) ----
      if (on.type==0 || on.type==1){
        const bf16* px = xTc + ((size_t)on.t*16 + l15)*96 + 8*q;
        #pragma unroll
        for (int s=0;s<3;++s) pX[s] = *(const bf16x8_t*)(px + 32*s);
      }
      // ---- BCELL: save pre-update h_back (= h_back_dict[t+1]) ----
      if (op.type==0 && op.save>=0){
        bf16* sp = savc + (int)op.save*1696;
        #pragma unroll
        for (int g=0; g<7; ++g){
          int j = 16*g + l15;
          if (j < 100){
            #pragma unroll
            for (int i=0;i<4;++i) sp[(4*q+i)*104 + j] = __float2bfloat16(hb_reg[g][i]);
          }
        }
      }
      // ---- MFMAs: z,r fused (x@W + h@U); n split (r multiplies only h-part) ----
      f32x4_t accZ[7], accR[7], accHn[7], accXn[7];
      #pragma unroll
      for (int g=0; g<7; ++g){
        accZ[g]=(f32x4_t){0,0,0,0}; accR[g]=(f32x4_t){0,0,0,0};
        accHn[g]=(f32x4_t){0,0,0,0}; accXn[g]=(f32x4_t){0,0,0,0};
      }
      { const bf16* Up = fwd? Uf : Ub;
        #pragma unroll
        for (int g=0; g<7; ++g){
          const bf16* bp = Up + (size_t)(48*g + l15)*128 + 8*q;
          #pragma unroll
          for (int s=0;s<4;++s){
            MFMA(accZ[g],  aH[s], *(const bf16x8_t*)(bp + 32*s));
            MFMA(accR[g],  aH[s], *(const bf16x8_t*)(bp + 16*128 + 32*s));
            MFMA(accHn[g], aH[s], *(const bf16x8_t*)(bp + 32*128 + 32*s));
          }
        }
      }
      if (hasX){
        const bf16* Wp = fwd? Wf : Wb;
        #pragma unroll
        for (int g=0; g<7; ++g){
          const bf16* bp = Wp + (size_t)(48*g + l15)*128 + 8*q;
          #pragma unroll
          for (int s=0;s<3;++s){
            MFMA(accZ[g],  aX[s], *(const bf16x8_t*)(bp + 32*s));
            MFMA(accR[g],  aX[s], *(const bf16x8_t*)(bp + 16*128 + 32*s));
            MFMA(accXn[g], aX[s], *(const bf16x8_t*)(bp + 32*128 + 32*s));
          }
        }
      }
      // ---- gate stage (lane-local; no barrier: same-wave LDS ordering suffices) ----
      bf16* wr = fwd? s_h : s_hbk;
      bf16* splw = (isCH && op.aux>=0)? (splc + (int)op.aux*1696) : (bf16*)nullptr;
      #pragma unroll
      for (int g=0; g<7; ++g){
        int j = 16*g + l15;
        if (j < 100){
          float bzs_ = fwd? bzsF[g] : bzsB[g];
          float brs_ = fwd? brsF[g] : brsB[g];
          float b0n_ = fwd? b0nF[g] : b0nB[g];
          float b1n_ = fwd? b1nF[g] : b1nB[g];
          #pragma unroll
          for (int i=0;i<4;++i){
            float az = accZ[g][i] + bzs_; az = fminf(fmaxf(az,-30.f),30.f);
            float ar = accR[g][i] + brs_; ar = fminf(fmaxf(ar,-30.f),30.f);
            float z  = 1.f/(1.f+__expf(-az));
            float rg = 1.f/(1.f+__expf(-ar));
            float an = accXn[g][i] + b0n_ + rg*(accHn[g][i] + b1n_);
            an = fminf(fmaxf(an,-15.f),15.f);
            float e2 = __expf(2.f*an);
            float nn = (e2-1.f)/(e2+1.f);
            float hold;
            if (fwd) hold = h_reg[g][i];
            else if (op.hsrc==0) hold = hb_reg[g][i];
            else hold = holdv[g][i];
            float hnew = z*hold + (1.f-z)*nn;
            if (fwd) h_reg[g][i]=hnew; else hb_reg[g][i]=hnew;
            wr[(4*q+i)*104 + j] = __float2bfloat16(hnew);
            if (splw) splw[(4*q+i)*104 + j] = __float2bfloat16(hnew);
          }
        }
      }
    } else {
      // ---- DEC: dec = relu([h,hb]@decW+db); mean = dec@meanW+mb -> out + ring slot ----
      const int lvl = op.lvl, t = op.t, wslot = op.save;
      bf16x8_t aG[8];
      { const bf16* hp = s_h + l15*104 + 8*q;
        #pragma unroll
        for (int s=0;s<4;++s) aG[s] = *(const bf16x8_t*)(hp + 32*s); }
      if (op.hsrc==0){
        const bf16* hp = s_hbk + l15*104 + 8*q;
        #pragma unroll
        for (int s=0;s<4;++s) aG[4+s] = *(const bf16x8_t*)(hp + 32*s);
      } else {
        const bf16* hp = ((op.hsrc==1)? savc : splc) + (int)op.srcidx*1696 + l15*104 + 8*q;
        #pragma unroll
        for (int s=0;s<4;++s) aG[4+s] = *(const bf16x8_t*)(hp + 32*s);
      }
      if (on.type==0 || on.type==1){
        const bf16* px = xTc + ((size_t)on.t*16 + l15)*96 + 8*q;
        #pragma unroll
        for (int s=0;s<3;++s) pX[s] = *(const bf16x8_t*)(px + 32*s);
      }
      // gemm1: [16,256] x [256 -> 64]
      #pragma unroll
      for (int gn=0; gn<4; ++gn){
        int c = 16*gn + l15;
        const bf16* bp = dW + ((size_t)(lvl*64 + c))*256 + 8*q;
        f32x4_t a1=(f32x4_t){0,0,0,0}, a2=(f32x4_t){0,0,0,0};
        #pragma unroll
        for (int s=0;s<8;s+=2){
          MFMA(a1, aG[s],   *(const bf16x8_t*)(bp + 32*s));
          MFMA(a2, aG[s+1], *(const bf16x8_t*)(bp + 32*(s+1)));
        }
        float db = cst[1600 + lvl*64 + c];
        #pragma unroll
        for (int i=0;i<4;++i){
          float v = fmaxf(a1[i]+a2[i]+db, 0.f);
          s_dec[(4*q+i)*72 + c] = __float2bfloat16(v);
        }
      }
      // gemm2: A=dec [16,64]
      bf16x8_t aD[2];
      #pragma unroll
      for (int s=0;s<2;++s) aD[s] = *(const bf16x8_t*)(s_dec + l15*72 + 8*q + 32*s);
      bf16* ringw = ringc + wslot*1536;
      #pragma unroll
      for (int gn=0; gn<4; ++gn){
        int c = 16*gn + l15;
        const bf16* bp = MW + ((size_t)(lvl*64 + c))*64 + 8*q;
        f32x4_t am=(f32x4_t){0,0,0,0};
        MFMA(am, aD[0], *(const bf16x8_t*)(bp));
        MFMA(am, aD[1], *(const bf16x8_t*)(bp + 32));
        float mb = cst[1344 + lvl*64 + c];
        #pragma unroll
        for (int i=0;i<4;++i){
          int r = 4*q+i; size_t b = (size_t)ci*16 + r;
          float m = am[i] + mb;
          ringw[r*96 + c] = __float2bfloat16(m);
          if (c >= 1) out[(b*64 + (c-1))*256 + t] = m;
          else        out[(b*64 + 63)*256 + t] = 1.0f;
        }
      }
      if (l15==0){
        bf16 one = __float2bfloat16(1.0f);
        #pragma unroll
        for (int i=0;i<4;++i) ringw[(4*q+i)*96 + 64] = one;
      }
    }
  }
}

// ---------------- launch ----------------
extern "C" void kernel_launch(void* const* d_in, const int* in_sizes, int n_in,
                              void* d_out, int out_size, void* d_ws, size_t ws_size,
                              hipStream_t stream){
  (void)out_size;
  const float *a=nullptr,*gru_W=nullptr,*gru_U=nullptr,*gru_b=nullptr,*bgru_W=nullptr,
              *bgru_U=nullptr,*bgru_b=nullptr,*dec_W=nullptr,*dec_b=nullptr,
              *mean_W=nullptr,*mean_b=nullptr;
  int nU=0, nb6=0;
  for (int i=0;i<n_in;++i){
    const float* p=(const float*)d_in[i]; int s=in_sizes[i];
    if      (s==25165824) a=p;
    else if (s==19200)    gru_W=p;
    else if (s==19500)    bgru_W=p;
    else if (s==30000)    { if(nU++==0) gru_U=p; else bgru_U=p; }
    else if (s==600)      { if(nb6++==0) gru_b=p; else bgru_b=p; }
    else if (s==40000)    dec_W=p;
    else if (s==200)      dec_b=p;
    else if (s==12800)    mean_W=p;
    else if (s==256)      mean_b=p;
  }
  if (!a||!gru_W||!gru_U||!gru_b||!bgru_W||!bgru_U||!bgru_b||!dec_W||!dec_b||!mean_W||!mean_b){
    a=(const float*)d_in[0]; gru_W=(const float*)d_in[1]; gru_U=(const float*)d_in[2];
    gru_b=(const float*)d_in[3]; bgru_W=(const float*)d_in[4]; bgru_U=(const float*)d_in[5];
    bgru_b=(const float*)d_in[6]; dec_W=(const float*)d_in[7]; dec_b=(const float*)d_in[8];
    mean_W=(const float*)d_in[9]; mean_b=(const float*)d_in[10];
  }
  unsigned char* ws = (unsigned char*)d_ws;
  float* out = (float*)d_out;

  k_obs  <<<512,  64, 0, stream>>>(a, out);
  if (ws_size < WS_NEED) return;

  k_xt   <<<512, 256, 0, stream>>>(a, (bf16*)(ws+XT_OFF));
  k_wt   <<<336, 128, 0, stream>>>(gru_U, bgru_U, gru_W, bgru_W,
                                   (bf16*)(ws+UF_OFF), (bf16*)(ws+UB_OFF),
                                   (bf16*)(ws+WF_OFF), (bf16*)(ws+WB_OFF));
  k_decw <<<256, 256, 0, stream>>>(dec_W, (bf16*)(ws+DW_OFF));
  k_mw   <<<256,  64, 0, stream>>>(mean_W, (bf16*)(ws+MW_OFF));
  k_consts<<<1,  256, 0, stream>>>(gru_b, bgru_b, mean_b, dec_b, (float*)(ws+CST_OFF));
  naomi_main<<<8, 256, 0, stream>>>(ws, out);
}